// Round 12
// baseline (82.680 us; speedup 1.0000x reference)
//
#include <hip/hip_runtime.h>

// SequentialSparsemax: (8, 16, 262144) f32.
// pass1: sparsemax over 16 instruments at every (b, t).
// pass2: sparsemax over each 64-sample frame per (b, inst).
//
// r11's packed-f16 design with FULL-GRID RESIDENCY: grid = 2048 WGs =
// exactly 8 WGs/CU, and LDS cut to 16 KiB/WG (NSLOT=8, 2 staging rounds
// of 8 insts) so all 8 WGs fit on a CU at once (128 KiB LDS, VGPR<=64).
// This removes the 2-span schedule + tail that pinned occupancy at
// ~50-60% of the static cap in every earlier round.
//   pass1: Ah[16][2] u32 (2 times/reg); packed OEMS-16 (v_pk_max/min)
//          sorts both times at once; tau in f32 via inline unpack.
//   pass2: w[32] packed (e,e+32): 480/543 OEMS-64 CEs are lo/hi pairs;
//          32 within-reg + 31 cross CEs use merge forms.
//   staging: xor-8 ds_swizzle partner exchange builds (t,t+32) dwords;
//          8-slot LDS (4 KiB/wave), rounds {0..7}, {8..15}; insts 0..7
//          recomputed from Ah at phase 3 (2 pk ops each).

#define T_DIM   262144
#define N_INST  16
#define B_DIM   8
#define CHUNK   256                   // time samples per wave-tile (4 frames)
#define NCHUNK  (T_DIM / CHUNK)       // 1024
#define WPB     4                     // independent waves per block
#define NSLOT   8                     // LDS slots per wave (8 x 128 dwords)

// ---- packed-f16 micro-ops (u32 = 2 x f16) ----
__device__ __forceinline__ unsigned pk_max(unsigned a, unsigned b) {
  unsigned r; asm("v_pk_max_f16 %0, %1, %2" : "=v"(r) : "v"(a), "v"(b)); return r;
}
__device__ __forceinline__ unsigned pk_min(unsigned a, unsigned b) {
  unsigned r; asm("v_pk_min_f16 %0, %1, %2" : "=v"(r) : "v"(a), "v"(b)); return r;
}
__device__ __forceinline__ unsigned pk_add(unsigned a, unsigned b) {
  unsigned r; asm("v_pk_add_f16 %0, %1, %2" : "=v"(r) : "v"(a), "v"(b)); return r;
}
__device__ __forceinline__ unsigned f2h(float x) {   // low16 valid, RNE
  unsigned r; asm("v_cvt_f16_f32 %0, %1" : "=v"(r) : "v"(x)); return r;
}
__device__ __forceinline__ float h2f(unsigned x) {   // converts low16
  float r; asm("v_cvt_f32_f16 %0, %1" : "=v"(r) : "v"(x)); return r;
}
__device__ __forceinline__ unsigned hswap(unsigned x) { return (x >> 16) | (x << 16); }
__device__ __forceinline__ unsigned lh(unsigned lo, unsigned hi) {
  return (lo & 0xFFFFu) | (hi & 0xFFFF0000u);   // [lo.lo16, hi.hi16] -> v_bfi
}
__device__ __forceinline__ unsigned packh(unsigned lo, unsigned hi) {
  return (lo & 0xFFFFu) | (hi << 16);           // both low16-valid inputs
}

// ---- CE helpers: float (scalar) and unsigned (packed f16 pair) ----
__device__ __forceinline__ float    ce_max(float a, float b)       { return fmaxf(a, b); }
__device__ __forceinline__ float    ce_min(float a, float b)       { return fminf(a, b); }
__device__ __forceinline__ unsigned ce_max(unsigned a, unsigned b) { return pk_max(a, b); }
__device__ __forceinline__ unsigned ce_min(unsigned a, unsigned b) { return pk_min(a, b); }

// Batcher odd-even mergesort, descending (max to lower index); all indices
// compile-time after unroll. For T=unsigned each register half is an
// independent problem (packed SIMD sort).
template<typename T, int N>
__device__ __forceinline__ void sort_desc_oems(T (&a)[N]) {
#pragma unroll
  for (int p = 1; p < N; p <<= 1) {
#pragma unroll
    for (int k = p; k >= 1; k >>= 1) {
#pragma unroll
      for (int j = k & (p - 1); j + k < N; j += 2 * k) {
#pragma unroll
        for (int i = 0; i < k; ++i) {
          if (i + j + k < N && (i + j) / (2 * p) == (i + j + k) / (2 * p)) {
            const T x = a[i + j], y = a[i + j + k];
            a[i + j]     = ce_max(x, y);
            a[i + j + k] = ce_min(x, y);
          }
        }
      }
    }
  }
}

// OEMS-64 on (e, e+32) split-packing: reg r = [pos r, pos r+32].
// CE classes: both<32 -> plain pk pair (hi companion provably in network);
// y==x+32 -> within-register; x<32<=y -> cross (reg x lo <-> reg y-32 hi).
__device__ __forceinline__ void sort64_packed(unsigned (&a)[32]) {
#pragma unroll
  for (int p = 1; p < 64; p <<= 1) {
#pragma unroll
    for (int k = p; k >= 1; k >>= 1) {
#pragma unroll
      for (int j = k & (p - 1); j + k < 64; j += 2 * k) {
#pragma unroll
        for (int i = 0; i < k; ++i) {
          const int x = i + j, y = i + j + k;
          if (y < 64 && (x / (2 * p)) == (y / (2 * p))) {
            if (y < 32) {
              const unsigned A = a[x], B = a[y];
              a[x] = pk_max(A, B); a[y] = pk_min(A, B);
            } else if (x < 32) {
              if (y == x + 32) {              // within-register: [max,min]
                const unsigned A = a[x], S = hswap(A);
                a[x] = lh(pk_max(A, S), pk_min(A, S));
              } else {                        // cross: x lo <-> (y-32) hi
                const int ry = y - 32;
                const unsigned A = a[x], B = a[ry], Bs = hswap(B);
                const unsigned M = pk_max(A, Bs), m = pk_min(A, Bs);
                a[x]  = lh(M, A);             // lo=max(A.lo,B.hi), hi kept
                a[ry] = lh(B, hswap(m));      // lo kept, hi=min(A.lo,B.hi)
              }
            }
          }
        }
      }
    }
  }
}

// lgkm-only fence: orders this wave's own-LDS ops without draining vmcnt.
// Waves in the block use disjoint LDS slices => no s_barrier.
__device__ __forceinline__ void lds_fence() {
  asm volatile("s_waitcnt lgkmcnt(0)" ::: "memory");
  __builtin_amdgcn_sched_barrier(0);
}

__device__ __forceinline__ unsigned swz_xor8(unsigned x) {
  return (unsigned)__builtin_amdgcn_ds_swizzle((int)x, (8 << 10) | 0x1f);
}

__global__ __launch_bounds__(256, 8) void seq_sparsemax_kernel(
    const float* __restrict__ in, float* __restrict__ out) {
  __shared__ __align__(16) unsigned lds[WPB * NSLOT * 128];  // 16 KiB

  const int lane = threadIdx.x & 63;
  const int wave = threadIdx.x >> 6;
  unsigned* __restrict__ sp = &lds[wave * NSLOT * 128];

  const int tid   = blockIdx.x * WPB + wave;   // tile index 0..8191
  const int b     = tid >> 10;
  const int chunk = tid & (NCHUNK - 1);
  const size_t base = (size_t)b * N_INST * T_DIM + (size_t)chunk * CHUNK + 4 * lane;

  const int f    = lane >> 4;          // this lane's frame (of 4)
  const int lt0  = 4 * (lane & 15);    // local time in frame, 0..60
  const bool lol = (lane & 8) == 0;    // lt0 < 32 (owns packed-dword writes)

  // ---- load float4, convert to packed f16: Ah[i] = [(t0,t1),(t2,t3)] ----
  unsigned Ah[N_INST][2];
#pragma unroll
  for (int i = 0; i < N_INST; ++i) {
    const float4 q = *reinterpret_cast<const float4*>(in + base + (size_t)i * T_DIM);
    Ah[i][0] = packh(f2h(q.x), f2h(q.y));
    Ah[i][1] = packh(f2h(q.z), f2h(q.w));
  }

  // ---- pass 1: packed OEMS-16 sorts both times of a pair at once ----
  unsigned nt2[2];   // packed negated taus, [-tau_even, -tau_odd]
#pragma unroll
  for (int p = 0; p < 2; ++p) {
    unsigned z[N_INST];
#pragma unroll
    for (int i = 0; i < N_INST; ++i) z[i] = Ah[i][p];
    sort_desc_oems<unsigned, N_INST>(z);
    float csl = 0.f, csh = 0.f, tl = -1e30f, th = -1e30f;
#pragma unroll
    for (int k = 0; k < N_INST; ++k) {
      csl += h2f(z[k]);       tl = fmaxf(tl, (csl - 1.f) * (1.f / (float)(k + 1)));
      csh += h2f(z[k] >> 16); th = fmaxf(th, (csh - 1.f) * (1.f / (float)(k + 1)));
    }
    nt2[p] = packh(f2h(tl), f2h(th)) ^ 0x80008000u;   // negate both halves
  }

  const unsigned zz = 0u;  // Y(i,p) = pk_max(Ah + (-tau), 0)

  // ---- staging + gather, 2 rounds of 8 insts (8-slot LDS) ----
  // logical dword d of (slot s, frame fr) holds times (d, d+32) of the row;
  // physical dword = s*128 + fr*32 + (d ^ (s<<2)).
  const int i2 = lane & 15;            // this lane's pass-2 row: inst
  const int f2 = lane >> 4;            //                         frame
  unsigned w[32];

#pragma unroll
  for (int g = 0; g < 2; ++g) {
    if (g > 0) lds_fence();            // WAR: round-0 reads done
#pragma unroll
    for (int i = 8 * g; i < 8 * g + 8; ++i) {
      const unsigned y0 = pk_max(pk_add(Ah[i][0], nt2[0]), zz);
      const unsigned y1 = pk_max(pk_add(Ah[i][1], nt2[1]), zz);
      const unsigned p0 = swz_xor8(y0);   // partner lane (^8): times +32
      const unsigned p1 = swz_xor8(y1);
      if (lol) {
        uint4 d;
        d.x = packh(y0, p0);              // [t=lt0+0, t+32]
        d.y = lh(y0 >> 16, p0);           // [t=lt0+1, t+32]
        d.z = packh(y1, p1);              // [t=lt0+2, t+32]
        d.w = lh(y1 >> 16, p1);           // [t=lt0+3, t+32]
        const int s = i & 7;
        const int pd = s * 128 + f * 32 + (lt0 ^ (s << 2));
        *reinterpret_cast<uint4*>(&sp[pd]) = d;
      }
    }
    lds_fence();                        // RAW: writes visible
    if ((i2 >> 3) == g) {
      const int s = i2 & 7;
#pragma unroll
      for (int v = 0; v < 8; ++v) {
        const int pd = s * 128 + f2 * 32 + ((4 * v) ^ (s << 2));
        const uint4 d = *reinterpret_cast<const uint4*>(&sp[pd]);
        w[4 * v + 0] = d.x; w[4 * v + 1] = d.y;
        w[4 * v + 2] = d.z; w[4 * v + 3] = d.w;
      }
    }
  }

  // ---- pass 2: packed sort of this lane's 64-row, then tau (f32) ----
  sort64_packed(w);
  float cs = 0.f, best = -1e30f;
#pragma unroll
  for (int r = 0; r < 32; ++r) {        // ranks 1..32 (lo halves)
    cs += h2f(w[r]);
    best = fmaxf(best, (cs - 1.f) * (1.f / (float)(r + 1)));
  }
#pragma unroll
  for (int r = 0; r < 32; ++r) {        // ranks 33..64 (hi halves)
    cs += h2f(w[r] >> 16);
    best = fmaxf(best, (cs - 1.f) * (1.f / (float)(r + 33)));
  }
  __builtin_amdgcn_sched_barrier(0);    // don't hoist phase 3 into the sort

  // ---- phase 3: pull row-taus; Y from LDS (i>=8) or recompute (i<8) ----
  const int slb = lane & 48;            // (lane>>4)*16: row-owner lane base
  const unsigned hsh = (lane & 8) ? 16u : 0u;   // my half in packed dwords
#pragma unroll
  for (int i = 0; i < N_INST; ++i) {
    const float taui = __int_as_float(__builtin_amdgcn_ds_bpermute(
        (slb | i) << 2, __float_as_int(best)));
    float y0, y1, y2, y3;
    if (i < 8) {                        // slots overwritten: recompute from Ah
      const unsigned a0 = pk_max(pk_add(Ah[i][0], nt2[0]), zz);
      const unsigned a1 = pk_max(pk_add(Ah[i][1], nt2[1]), zz);
      y0 = h2f(a0); y1 = h2f(a0 >> 16); y2 = h2f(a1); y3 = h2f(a1 >> 16);
    } else {
      const int s = i & 7;
      const int pd = s * 128 + f * 32 + ((lt0 & 31) ^ (s << 2));
      const uint4 d = *reinterpret_cast<const uint4*>(&sp[pd]);
      y0 = h2f(d.x >> hsh); y1 = h2f(d.y >> hsh);
      y2 = h2f(d.z >> hsh); y3 = h2f(d.w >> hsh);
    }
    float4 o;
    o.x = fmaxf(y0 - taui, 0.0f);
    o.y = fmaxf(y1 - taui, 0.0f);
    o.z = fmaxf(y2 - taui, 0.0f);
    o.w = fmaxf(y3 - taui, 0.0f);
    *reinterpret_cast<float4*>(out + base + (size_t)i * T_DIM) = o;
  }
}

extern "C" void kernel_launch(void* const* d_in, const int* in_sizes, int n_in,
                              void* d_out, int out_size, void* d_ws, size_t ws_size,
                              hipStream_t stream) {
  const float* in = (const float*)d_in[0];
  float* out = (float*)d_out;
  const int grid = B_DIM * NCHUNK / WPB;  // 2048 blocks = 8 per CU, all resident
  seq_sparsemax_kernel<<<grid, 64 * WPB, 0, stream>>>(in, out);
}

// Round 13
// 77.867 us; speedup vs baseline: 1.0618x; 1.0618x over previous
//
#include <hip/hip_runtime.h>

// SequentialSparsemax: (8, 16, 262144) f32.
// pass1: sparsemax over 16 instruments at every (b, t).
// pass2: sparsemax over each 64-sample frame per (b, inst).
//
// r11's packed-f16 design at the register/LDS sweet spot: NSLOT=10
// (5 KiB/wave, 20 KiB/WG) -> exactly 8 WGs/CU resident (160 KiB LDS),
// matching the 2048-WG grid in ONE span (no occupancy tail), while the
// staging-peak live set stays 58 regs (w32 + Ah[10..15] + Ah[0..5] + nt2)
// so __launch_bounds__(256,8) fits without scratch (r12's failure mode:
// NSLOT=8 -> 66 live -> VGPR 32 + 108 MB scratch traffic).
//   pass1: Ah[16][2] u32 (2 times/reg); packed OEMS-16 (v_pk_max/min)
//          sorts both times at once; tau in f32 via inline unpack.
//   pass2: w[32] packed (e,e+32): 480/543 OEMS-64 CEs are lo/hi pairs;
//          32 within-reg + 31 cross CEs use merge forms.
//   staging: xor-8 ds_swizzle partner exchange builds (t,t+32) dwords;
//          rounds {0..9}->slots 0..9, {10..15}->slots 0..5; phase 3
//          recomputes i<6 from Ah+nt2, reads i=6..9 (slots 6..9) and
//          i>=10 (slots 0..5) from LDS.

#define T_DIM   262144
#define N_INST  16
#define B_DIM   8
#define CHUNK   256                   // time samples per wave-tile (4 frames)
#define NCHUNK  (T_DIM / CHUNK)       // 1024
#define WPB     4                     // independent waves per block
#define NSLOT   10                    // LDS slots per wave (10 x 128 dwords)

// ---- packed-f16 micro-ops (u32 = 2 x f16) ----
__device__ __forceinline__ unsigned pk_max(unsigned a, unsigned b) {
  unsigned r; asm("v_pk_max_f16 %0, %1, %2" : "=v"(r) : "v"(a), "v"(b)); return r;
}
__device__ __forceinline__ unsigned pk_min(unsigned a, unsigned b) {
  unsigned r; asm("v_pk_min_f16 %0, %1, %2" : "=v"(r) : "v"(a), "v"(b)); return r;
}
__device__ __forceinline__ unsigned pk_add(unsigned a, unsigned b) {
  unsigned r; asm("v_pk_add_f16 %0, %1, %2" : "=v"(r) : "v"(a), "v"(b)); return r;
}
__device__ __forceinline__ unsigned f2h(float x) {   // low16 valid, RNE
  unsigned r; asm("v_cvt_f16_f32 %0, %1" : "=v"(r) : "v"(x)); return r;
}
__device__ __forceinline__ float h2f(unsigned x) {   // converts low16
  float r; asm("v_cvt_f32_f16 %0, %1" : "=v"(r) : "v"(x)); return r;
}
__device__ __forceinline__ unsigned hswap(unsigned x) { return (x >> 16) | (x << 16); }
__device__ __forceinline__ unsigned lh(unsigned lo, unsigned hi) {
  return (lo & 0xFFFFu) | (hi & 0xFFFF0000u);   // [lo.lo16, hi.hi16] -> v_bfi
}
__device__ __forceinline__ unsigned packh(unsigned lo, unsigned hi) {
  return (lo & 0xFFFFu) | (hi << 16);           // both low16-valid inputs
}

// ---- CE helpers: float (scalar) and unsigned (packed f16 pair) ----
__device__ __forceinline__ float    ce_max(float a, float b)       { return fmaxf(a, b); }
__device__ __forceinline__ float    ce_min(float a, float b)       { return fminf(a, b); }
__device__ __forceinline__ unsigned ce_max(unsigned a, unsigned b) { return pk_max(a, b); }
__device__ __forceinline__ unsigned ce_min(unsigned a, unsigned b) { return pk_min(a, b); }

// Batcher odd-even mergesort, descending (max to lower index); all indices
// compile-time after unroll. For T=unsigned each register half is an
// independent problem (packed SIMD sort).
template<typename T, int N>
__device__ __forceinline__ void sort_desc_oems(T (&a)[N]) {
#pragma unroll
  for (int p = 1; p < N; p <<= 1) {
#pragma unroll
    for (int k = p; k >= 1; k >>= 1) {
#pragma unroll
      for (int j = k & (p - 1); j + k < N; j += 2 * k) {
#pragma unroll
        for (int i = 0; i < k; ++i) {
          if (i + j + k < N && (i + j) / (2 * p) == (i + j + k) / (2 * p)) {
            const T x = a[i + j], y = a[i + j + k];
            a[i + j]     = ce_max(x, y);
            a[i + j + k] = ce_min(x, y);
          }
        }
      }
    }
  }
}

// OEMS-64 on (e, e+32) split-packing: reg r = [pos r, pos r+32].
// CE classes: both<32 -> plain pk pair (hi companion provably in network);
// y==x+32 -> within-register; x<32<=y -> cross (reg x lo <-> reg y-32 hi).
__device__ __forceinline__ void sort64_packed(unsigned (&a)[32]) {
#pragma unroll
  for (int p = 1; p < 64; p <<= 1) {
#pragma unroll
    for (int k = p; k >= 1; k >>= 1) {
#pragma unroll
      for (int j = k & (p - 1); j + k < 64; j += 2 * k) {
#pragma unroll
        for (int i = 0; i < k; ++i) {
          const int x = i + j, y = i + j + k;
          if (y < 64 && (x / (2 * p)) == (y / (2 * p))) {
            if (y < 32) {
              const unsigned A = a[x], B = a[y];
              a[x] = pk_max(A, B); a[y] = pk_min(A, B);
            } else if (x < 32) {
              if (y == x + 32) {              // within-register: [max,min]
                const unsigned A = a[x], S = hswap(A);
                a[x] = lh(pk_max(A, S), pk_min(A, S));
              } else {                        // cross: x lo <-> (y-32) hi
                const int ry = y - 32;
                const unsigned A = a[x], B = a[ry], Bs = hswap(B);
                const unsigned M = pk_max(A, Bs), m = pk_min(A, Bs);
                a[x]  = lh(M, A);             // lo=max(A.lo,B.hi), hi kept
                a[ry] = lh(B, hswap(m));      // lo kept, hi=min(A.lo,B.hi)
              }
            }
          }
        }
      }
    }
  }
}

// lgkm-only fence: orders this wave's own-LDS ops without draining vmcnt.
// Waves in the block use disjoint LDS slices => no s_barrier.
__device__ __forceinline__ void lds_fence() {
  asm volatile("s_waitcnt lgkmcnt(0)" ::: "memory");
  __builtin_amdgcn_sched_barrier(0);
}

__device__ __forceinline__ unsigned swz_xor8(unsigned x) {
  return (unsigned)__builtin_amdgcn_ds_swizzle((int)x, (8 << 10) | 0x1f);
}

__global__ __launch_bounds__(256, 8) void seq_sparsemax_kernel(
    const float* __restrict__ in, float* __restrict__ out) {
  __shared__ __align__(16) unsigned lds[WPB * NSLOT * 128];  // 20 KiB

  const int lane = threadIdx.x & 63;
  const int wave = threadIdx.x >> 6;
  unsigned* __restrict__ sp = &lds[wave * NSLOT * 128];

  const int tid   = blockIdx.x * WPB + wave;   // tile index 0..8191
  const int b     = tid >> 10;
  const int chunk = tid & (NCHUNK - 1);
  const size_t base = (size_t)b * N_INST * T_DIM + (size_t)chunk * CHUNK + 4 * lane;

  const int f    = lane >> 4;          // this lane's frame (of 4)
  const int lt0  = 4 * (lane & 15);    // local time in frame, 0..60
  const bool lol = (lane & 8) == 0;    // lt0 < 32 (owns packed-dword writes)

  // ---- load float4, convert to packed f16: Ah[i] = [(t0,t1),(t2,t3)] ----
  unsigned Ah[N_INST][2];
#pragma unroll
  for (int i = 0; i < N_INST; ++i) {
    const float4 q = *reinterpret_cast<const float4*>(in + base + (size_t)i * T_DIM);
    Ah[i][0] = packh(f2h(q.x), f2h(q.y));
    Ah[i][1] = packh(f2h(q.z), f2h(q.w));
  }

  // ---- pass 1: packed OEMS-16 sorts both times of a pair at once ----
  unsigned nt2[2];   // packed negated taus, [-tau_even, -tau_odd]
#pragma unroll
  for (int p = 0; p < 2; ++p) {
    unsigned z[N_INST];
#pragma unroll
    for (int i = 0; i < N_INST; ++i) z[i] = Ah[i][p];
    sort_desc_oems<unsigned, N_INST>(z);
    float csl = 0.f, csh = 0.f, tl = -1e30f, th = -1e30f;
#pragma unroll
    for (int k = 0; k < N_INST; ++k) {
      csl += h2f(z[k]);       tl = fmaxf(tl, (csl - 1.f) * (1.f / (float)(k + 1)));
      csh += h2f(z[k] >> 16); th = fmaxf(th, (csh - 1.f) * (1.f / (float)(k + 1)));
    }
    nt2[p] = packh(f2h(tl), f2h(th)) ^ 0x80008000u;   // negate both halves
  }

  const unsigned zz = 0u;  // Y(i,p) = pk_max(Ah + (-tau), 0)

  // ---- staging + gather, rounds {0..9} and {10..15} (10-slot LDS) ----
  // logical dword d of (slot s, frame fr) holds times (d, d+32) of the row;
  // physical dword = s*128 + fr*32 + (d ^ ((s&7)<<2)).
  const int i2 = lane & 15;            // this lane's pass-2 row: inst
  const int f2 = lane >> 4;            //                         frame
  unsigned w[32];

#pragma unroll
  for (int g = 0; g < 2; ++g) {
    if (g > 0) lds_fence();            // WAR: round-0 reads done
    const int i_lo = (g == 0) ? 0 : 10, i_hi = (g == 0) ? 10 : 16;
#pragma unroll
    for (int i = 0; i < N_INST; ++i) {
      if (i < i_lo || i >= i_hi) continue;
      const unsigned y0 = pk_max(pk_add(Ah[i][0], nt2[0]), zz);
      const unsigned y1 = pk_max(pk_add(Ah[i][1], nt2[1]), zz);
      const unsigned p0 = swz_xor8(y0);   // partner lane (^8): times +32
      const unsigned p1 = swz_xor8(y1);
      if (lol) {
        uint4 d;
        d.x = packh(y0, p0);              // [t=lt0+0, t+32]
        d.y = lh(y0 >> 16, p0);           // [t=lt0+1, t+32]
        d.z = packh(y1, p1);              // [t=lt0+2, t+32]
        d.w = lh(y1 >> 16, p1);           // [t=lt0+3, t+32]
        const int s = (i < 10) ? i : (i - 10);
        const int pd = s * 128 + f * 32 + (lt0 ^ ((s & 7) << 2));
        *reinterpret_cast<uint4*>(&sp[pd]) = d;
      }
    }
    lds_fence();                        // RAW: writes visible
    const bool mine = (g == 0) ? (i2 < 10) : (i2 >= 10);
    if (mine) {
      const int s = (i2 < 10) ? i2 : (i2 - 10);
#pragma unroll
      for (int v = 0; v < 8; ++v) {
        const int pd = s * 128 + f2 * 32 + ((4 * v) ^ ((s & 7) << 2));
        const uint4 d = *reinterpret_cast<const uint4*>(&sp[pd]);
        w[4 * v + 0] = d.x; w[4 * v + 1] = d.y;
        w[4 * v + 2] = d.z; w[4 * v + 3] = d.w;
      }
    }
  }

  // ---- pass 2: packed sort of this lane's 64-row, then tau (f32) ----
  sort64_packed(w);
  float cs = 0.f, best = -1e30f;
#pragma unroll
  for (int r = 0; r < 32; ++r) {        // ranks 1..32 (lo halves)
    cs += h2f(w[r]);
    best = fmaxf(best, (cs - 1.f) * (1.f / (float)(r + 1)));
  }
#pragma unroll
  for (int r = 0; r < 32; ++r) {        // ranks 33..64 (hi halves)
    cs += h2f(w[r] >> 16);
    best = fmaxf(best, (cs - 1.f) * (1.f / (float)(r + 33)));
  }
  __builtin_amdgcn_sched_barrier(0);    // don't hoist phase 3 into the sort

  // ---- phase 3: pull row-taus; Y from regs (i<6) or LDS (i>=6) ----
  const int slb = lane & 48;            // (lane>>4)*16: row-owner lane base
  const unsigned hsh = (lane & 8) ? 16u : 0u;   // my half in packed dwords
#pragma unroll
  for (int i = 0; i < N_INST; ++i) {
    const float taui = __int_as_float(__builtin_amdgcn_ds_bpermute(
        (slb | i) << 2, __float_as_int(best)));
    float y0, y1, y2, y3;
    if (i < 6) {                        // slots overwritten: recompute from Ah
      const unsigned a0 = pk_max(pk_add(Ah[i][0], nt2[0]), zz);
      const unsigned a1 = pk_max(pk_add(Ah[i][1], nt2[1]), zz);
      y0 = h2f(a0); y1 = h2f(a0 >> 16); y2 = h2f(a1); y3 = h2f(a1 >> 16);
    } else {
      const int s = (i < 10) ? i : (i - 10);
      const int pd = s * 128 + f * 32 + ((lt0 & 31) ^ ((s & 7) << 2));
      const uint4 d = *reinterpret_cast<const uint4*>(&sp[pd]);
      y0 = h2f(d.x >> hsh); y1 = h2f(d.y >> hsh);
      y2 = h2f(d.z >> hsh); y3 = h2f(d.w >> hsh);
    }
    float4 o;
    o.x = fmaxf(y0 - taui, 0.0f);
    o.y = fmaxf(y1 - taui, 0.0f);
    o.z = fmaxf(y2 - taui, 0.0f);
    o.w = fmaxf(y3 - taui, 0.0f);
    *reinterpret_cast<float4*>(out + base + (size_t)i * T_DIM) = o;
  }
}

extern "C" void kernel_launch(void* const* d_in, const int* in_sizes, int n_in,
                              void* d_out, int out_size, void* d_ws, size_t ws_size,
                              hipStream_t stream) {
  const float* in = (const float*)d_in[0];
  float* out = (float*)d_out;
  const int grid = B_DIM * NCHUNK / WPB;  // 2048 blocks = 8 per CU, one span
  seq_sparsemax_kernel<<<grid, 64 * WPB, 0, stream>>>(in, out);
}

// Round 14
// 52.862 us; speedup vs baseline: 1.5641x; 1.4730x over previous
//
#include <hip/hip_runtime.h>

// SequentialSparsemax: (8, 16, 262144) f32.
// pass1: sparsemax over 16 instruments at every (b, t).
// pass2: sparsemax over each 64-sample frame per (b, inst).
//
// r11's packed-f16 math with the register-liveness conflict removed:
// SINGLE-round staging of all 16 insts into a full 8 KiB/wave LDS tile
// (NSLOT=16, 32 KiB/WG) -> Ah/nt2 die at staging; phase 3 reads all rows
// from LDS. Peak live ~45 regs (w[32] + addressing) at a loose (256,4)
// budget -> no spill cliff (r12/r13 failure mode: partial-Ah recompute
// kept 8-12 regs live across the sort -> allocator scratch collapse).
// Residency: LDS caps 5 WG/CU; grid = 1024 WGs (4/CU, all resident,
// balanced), each wave processes 2 tiles (tid, tid+4096) in a rolled loop
// -> no second-span occupancy tail.
//   pass1: Ah[16][2] u32 (2 times/reg); packed OEMS-16 (v_pk_max/min)
//          sorts both times at once; tau in f32 via inline unpack.
//   pass2: w[32] packed (e,e+32): 480/543 OEMS-64 CEs are lo/hi pairs;
//          32 within-reg + 31 cross CEs use merge forms.
//   tau2:  lo/hi rank chains made independent (dh = csl-1) for ILP.

#define T_DIM   262144
#define N_INST  16
#define B_DIM   8
#define CHUNK   256                   // time samples per wave-tile (4 frames)
#define NCHUNK  (T_DIM / CHUNK)       // 1024
#define WPB     4                     // independent waves per block
#define NSLOT   16                    // full tile in LDS (16 x 128 dwords)
#define NTILES  8192                  // total wave-tiles
#define GRID    1024                  // 4 WG/CU, all resident, balanced
#define TPW     2                     // tiles per wave

// ---- packed-f16 micro-ops (u32 = 2 x f16) ----
__device__ __forceinline__ unsigned pk_max(unsigned a, unsigned b) {
  unsigned r; asm("v_pk_max_f16 %0, %1, %2" : "=v"(r) : "v"(a), "v"(b)); return r;
}
__device__ __forceinline__ unsigned pk_min(unsigned a, unsigned b) {
  unsigned r; asm("v_pk_min_f16 %0, %1, %2" : "=v"(r) : "v"(a), "v"(b)); return r;
}
__device__ __forceinline__ unsigned pk_add(unsigned a, unsigned b) {
  unsigned r; asm("v_pk_add_f16 %0, %1, %2" : "=v"(r) : "v"(a), "v"(b)); return r;
}
__device__ __forceinline__ unsigned f2h(float x) {   // low16 valid, RNE
  unsigned r; asm("v_cvt_f16_f32 %0, %1" : "=v"(r) : "v"(x)); return r;
}
__device__ __forceinline__ float h2f(unsigned x) {   // converts low16
  float r; asm("v_cvt_f32_f16 %0, %1" : "=v"(r) : "v"(x)); return r;
}
__device__ __forceinline__ unsigned hswap(unsigned x) { return (x >> 16) | (x << 16); }
__device__ __forceinline__ unsigned lh(unsigned lo, unsigned hi) {
  return (lo & 0xFFFFu) | (hi & 0xFFFF0000u);   // [lo.lo16, hi.hi16] -> v_bfi
}
__device__ __forceinline__ unsigned packh(unsigned lo, unsigned hi) {
  return (lo & 0xFFFFu) | (hi << 16);           // both low16-valid inputs
}

// ---- CE helpers ----
__device__ __forceinline__ unsigned ce_max(unsigned a, unsigned b) { return pk_max(a, b); }
__device__ __forceinline__ unsigned ce_min(unsigned a, unsigned b) { return pk_min(a, b); }

// Batcher odd-even mergesort, descending (max to lower index); all indices
// compile-time after unroll; each register half an independent problem.
template<typename T, int N>
__device__ __forceinline__ void sort_desc_oems(T (&a)[N]) {
#pragma unroll
  for (int p = 1; p < N; p <<= 1) {
#pragma unroll
    for (int k = p; k >= 1; k >>= 1) {
#pragma unroll
      for (int j = k & (p - 1); j + k < N; j += 2 * k) {
#pragma unroll
        for (int i = 0; i < k; ++i) {
          if (i + j + k < N && (i + j) / (2 * p) == (i + j + k) / (2 * p)) {
            const T x = a[i + j], y = a[i + j + k];
            a[i + j]     = ce_max(x, y);
            a[i + j + k] = ce_min(x, y);
          }
        }
      }
    }
  }
}

// OEMS-64 on (e, e+32) split-packing: reg r = [pos r, pos r+32].
__device__ __forceinline__ void sort64_packed(unsigned (&a)[32]) {
#pragma unroll
  for (int p = 1; p < 64; p <<= 1) {
#pragma unroll
    for (int k = p; k >= 1; k >>= 1) {
#pragma unroll
      for (int j = k & (p - 1); j + k < 64; j += 2 * k) {
#pragma unroll
        for (int i = 0; i < k; ++i) {
          const int x = i + j, y = i + j + k;
          if (y < 64 && (x / (2 * p)) == (y / (2 * p))) {
            if (y < 32) {
              const unsigned A = a[x], B = a[y];
              a[x] = pk_max(A, B); a[y] = pk_min(A, B);
            } else if (x < 32) {
              if (y == x + 32) {              // within-register: [max,min]
                const unsigned A = a[x], S = hswap(A);
                a[x] = lh(pk_max(A, S), pk_min(A, S));
              } else {                        // cross: x lo <-> (y-32) hi
                const int ry = y - 32;
                const unsigned A = a[x], B = a[ry], Bs = hswap(B);
                const unsigned M = pk_max(A, Bs), m = pk_min(A, Bs);
                a[x]  = lh(M, A);             // lo=max(A.lo,B.hi), hi kept
                a[ry] = lh(B, hswap(m));      // lo kept, hi=min(A.lo,B.hi)
              }
            }
          }
        }
      }
    }
  }
}

// lgkm-only fence: orders this wave's own-LDS ops without draining vmcnt.
// Waves in the block use disjoint LDS slices => no s_barrier.
__device__ __forceinline__ void lds_fence() {
  asm volatile("s_waitcnt lgkmcnt(0)" ::: "memory");
  __builtin_amdgcn_sched_barrier(0);
}

__device__ __forceinline__ unsigned swz_xor8(unsigned x) {
  return (unsigned)__builtin_amdgcn_ds_swizzle((int)x, (8 << 10) | 0x1f);
}

__global__ __launch_bounds__(256, 4) void seq_sparsemax_kernel(
    const float* __restrict__ in, float* __restrict__ out) {
  __shared__ __align__(16) unsigned lds[WPB * NSLOT * 128];  // 32 KiB

  const int lane = threadIdx.x & 63;
  const int wave = threadIdx.x >> 6;
  unsigned* __restrict__ sp = &lds[wave * NSLOT * 128];

  const int tid0 = blockIdx.x * WPB + wave;    // first tile of this wave

  const int f    = lane >> 4;          // this lane's frame (of 4)
  const int lt0  = 4 * (lane & 15);    // local time in frame, 0..60
  const bool lol = (lane & 8) == 0;    // lt0 < 32 (owns packed-dword writes)
  const int i2   = lane & 15;          // this lane's pass-2 row: inst
  const int f2   = lane >> 4;          //                         frame
  const int slb  = lane & 48;          // row-owner lane base for bpermute
  const unsigned hsh = (lane & 8) ? 16u : 0u;  // my half in packed dwords

#pragma unroll 1
  for (int it = 0; it < TPW; ++it) {
    const int tid   = tid0 + it * (NTILES / TPW);   // +4096
    const int b     = tid >> 10;
    const int chunk = tid & (NCHUNK - 1);
    const size_t base =
        (size_t)b * N_INST * T_DIM + (size_t)chunk * CHUNK + 4 * lane;

    // ---- load float4 -> packed f16: Ah[i] = [(t0,t1),(t2,t3)] ----
    unsigned Ah[N_INST][2];
#pragma unroll
    for (int i = 0; i < N_INST; ++i) {
      const float4 q =
          *reinterpret_cast<const float4*>(in + base + (size_t)i * T_DIM);
      Ah[i][0] = packh(f2h(q.x), f2h(q.y));
      Ah[i][1] = packh(f2h(q.z), f2h(q.w));
    }

    // ---- pass 1: packed OEMS-16 sorts both times at once ----
    unsigned nt2[2];   // packed negated taus, [-tau_even, -tau_odd]
#pragma unroll
    for (int p = 0; p < 2; ++p) {
      unsigned z[N_INST];
#pragma unroll
      for (int i = 0; i < N_INST; ++i) z[i] = Ah[i][p];
      sort_desc_oems<unsigned, N_INST>(z);
      float csl = 0.f, csh = 0.f, tl = -1e30f, th = -1e30f;
#pragma unroll
      for (int k = 0; k < N_INST; ++k) {
        csl += h2f(z[k]);       tl = fmaxf(tl, (csl - 1.f) * (1.f / (float)(k + 1)));
        csh += h2f(z[k] >> 16); th = fmaxf(th, (csh - 1.f) * (1.f / (float)(k + 1)));
      }
      nt2[p] = packh(f2h(tl), f2h(th)) ^ 0x80008000u;   // negate both halves
    }

    const unsigned zz = 0u;  // Y(i,p) = pk_max(Ah + (-tau), 0)

    // ---- single-round staging of ALL 16 insts; Ah/nt2 die here ----
    // logical dword d of (slot s, frame fr) holds times (d, d+32);
    // physical dword = s*128 + fr*32 + (d ^ ((s&7)<<2)).
    if (it > 0) lds_fence();   // WAR: prev iter's phase-3 reads done
#pragma unroll
    for (int i = 0; i < N_INST; ++i) {
      const unsigned y0 = pk_max(pk_add(Ah[i][0], nt2[0]), zz);
      const unsigned y1 = pk_max(pk_add(Ah[i][1], nt2[1]), zz);
      const unsigned p0 = swz_xor8(y0);   // partner lane (^8): times +32
      const unsigned p1 = swz_xor8(y1);
      if (lol) {
        uint4 d;
        d.x = packh(y0, p0);              // [t=lt0+0, t+32]
        d.y = lh(y0 >> 16, p0);           // [t=lt0+1, t+32]
        d.z = packh(y1, p1);              // [t=lt0+2, t+32]
        d.w = lh(y1 >> 16, p1);           // [t=lt0+3, t+32]
        const int pd = i * 128 + f * 32 + (lt0 ^ ((i & 7) << 2));
        *reinterpret_cast<uint4*>(&sp[pd]) = d;
      }
    }
    lds_fence();               // RAW: writes visible

    // ---- gather pass-2 row (inst i2, frame f2): 8 ranks per uint4 ----
    unsigned w[32];
#pragma unroll
    for (int v = 0; v < 8; ++v) {
      const int pd = i2 * 128 + f2 * 32 + ((4 * v) ^ ((i2 & 7) << 2));
      const uint4 d = *reinterpret_cast<const uint4*>(&sp[pd]);
      w[4 * v + 0] = d.x; w[4 * v + 1] = d.y;
      w[4 * v + 2] = d.z; w[4 * v + 3] = d.w;
    }

    // ---- pass 2: packed sort, then tau (f32, independent lo/hi chains) ----
    sort64_packed(w);
    float csl = 0.f, csh = 0.f, bl = -1e30f, bh = -1e30f;
#pragma unroll
    for (int r = 0; r < 32; ++r) {      // ranks 1..32 (lo halves)
      csl += h2f(w[r]);
      bl = fmaxf(bl, (csl - 1.f) * (1.f / (float)(r + 1)));
    }
    const float dh = csl - 1.f;         // hi chain offset
#pragma unroll
    for (int r = 0; r < 32; ++r) {      // ranks 33..64 (hi halves)
      csh += h2f(w[r] >> 16);
      bh = fmaxf(bh, (csh + dh) * (1.f / (float)(r + 33)));
    }
    const float best = fmaxf(bl, bh);
    __builtin_amdgcn_sched_barrier(0);  // don't hoist phase 3 into the sort

    // ---- phase 3: pull row-taus; read rows from LDS; store float4 ----
#pragma unroll
    for (int i = 0; i < N_INST; ++i) {
      const float taui = __int_as_float(__builtin_amdgcn_ds_bpermute(
          (slb | i) << 2, __float_as_int(best)));
      const int pd = i * 128 + f * 32 + ((lt0 & 31) ^ ((i & 7) << 2));
      const uint4 d = *reinterpret_cast<const uint4*>(&sp[pd]);
      float4 o;
      o.x = fmaxf(h2f(d.x >> hsh) - taui, 0.0f);
      o.y = fmaxf(h2f(d.y >> hsh) - taui, 0.0f);
      o.z = fmaxf(h2f(d.z >> hsh) - taui, 0.0f);
      o.w = fmaxf(h2f(d.w >> hsh) - taui, 0.0f);
      *reinterpret_cast<float4*>(out + base + (size_t)i * T_DIM) = o;
    }
  }
}

extern "C" void kernel_launch(void* const* d_in, const int* in_sizes, int n_in,
                              void* d_out, int out_size, void* d_ws, size_t ws_size,
                              hipStream_t stream) {
  const float* in = (const float*)d_in[0];
  float* out = (float*)d_out;
  seq_sparsemax_kernel<<<GRID, 64 * WPB, 0, stream>>>(in, out);
}

// Round 15
// 47.468 us; speedup vs baseline: 1.7418x; 1.1136x over previous
//
#include <hip/hip_runtime.h>

// SequentialSparsemax: (8, 16, 262144) f32.
// pass1: sparsemax over 16 instruments at every (b, t).
// pass2: sparsemax over each 64-sample frame per (b, inst).
//
// r11's packed-f16 design (best: 46.0 us, VGPR 44, zero scratch) with two
// residency/traffic knobs:
//  - WPB 4->2: 12 KiB/WG -> LDS cap 13 WG/CU (was 6), finer WG granularity
//    for the dispatcher; grid 4096.
//  - NON-TEMPORAL output stores: output is write-once/never-read; nt policy
//    stops it evicting the input from L3, so input stays cache-resident
//    across graph replays (FETCH was already 65.7 of 134 MB; should drop
//    further) -> HBM floor ~21-25 us.
//   pass1: Ah[16][2] u32 (2 times/reg); packed OEMS-16 (v_pk_max/min)
//          sorts both times at once; tau in f32 via inline unpack.
//   pass2: w[32] packed (e,e+32): 480/543 OEMS-64 CEs are lo/hi pairs;
//          32 within-reg + 31 cross CEs use merge forms.
//   staging: xor-8 ds_swizzle partner exchange builds (t,t+32) dwords;
//          12-slot LDS (6 KiB/wave), rounds {0..11}, {12..15}; insts 0..3
//          recomputed from Ah at phase 3 (r11-proven liveness, no spill).

#define T_DIM   262144
#define N_INST  16
#define B_DIM   8
#define CHUNK   256                   // time samples per wave-tile (4 frames)
#define NCHUNK  (T_DIM / CHUNK)       // 1024
#define WPB     2                     // independent waves per block
#define NSLOT   12                    // LDS slots per wave (12 x 128 dwords)

typedef float f32x4 __attribute__((ext_vector_type(4)));

// ---- packed-f16 micro-ops (u32 = 2 x f16) ----
__device__ __forceinline__ unsigned pk_max(unsigned a, unsigned b) {
  unsigned r; asm("v_pk_max_f16 %0, %1, %2" : "=v"(r) : "v"(a), "v"(b)); return r;
}
__device__ __forceinline__ unsigned pk_min(unsigned a, unsigned b) {
  unsigned r; asm("v_pk_min_f16 %0, %1, %2" : "=v"(r) : "v"(a), "v"(b)); return r;
}
__device__ __forceinline__ unsigned pk_add(unsigned a, unsigned b) {
  unsigned r; asm("v_pk_add_f16 %0, %1, %2" : "=v"(r) : "v"(a), "v"(b)); return r;
}
__device__ __forceinline__ unsigned f2h(float x) {   // low16 valid, RNE
  unsigned r; asm("v_cvt_f16_f32 %0, %1" : "=v"(r) : "v"(x)); return r;
}
__device__ __forceinline__ float h2f(unsigned x) {   // converts low16
  float r; asm("v_cvt_f32_f16 %0, %1" : "=v"(r) : "v"(x)); return r;
}
__device__ __forceinline__ unsigned hswap(unsigned x) { return (x >> 16) | (x << 16); }
__device__ __forceinline__ unsigned lh(unsigned lo, unsigned hi) {
  return (lo & 0xFFFFu) | (hi & 0xFFFF0000u);   // [lo.lo16, hi.hi16] -> v_bfi
}
__device__ __forceinline__ unsigned packh(unsigned lo, unsigned hi) {
  return (lo & 0xFFFFu) | (hi << 16);           // both low16-valid inputs
}

// ---- CE helpers ----
__device__ __forceinline__ unsigned ce_max(unsigned a, unsigned b) { return pk_max(a, b); }
__device__ __forceinline__ unsigned ce_min(unsigned a, unsigned b) { return pk_min(a, b); }

// Batcher odd-even mergesort, descending (max to lower index); all indices
// compile-time after unroll; each register half an independent problem.
template<typename T, int N>
__device__ __forceinline__ void sort_desc_oems(T (&a)[N]) {
#pragma unroll
  for (int p = 1; p < N; p <<= 1) {
#pragma unroll
    for (int k = p; k >= 1; k >>= 1) {
#pragma unroll
      for (int j = k & (p - 1); j + k < N; j += 2 * k) {
#pragma unroll
        for (int i = 0; i < k; ++i) {
          if (i + j + k < N && (i + j) / (2 * p) == (i + j + k) / (2 * p)) {
            const T x = a[i + j], y = a[i + j + k];
            a[i + j]     = ce_max(x, y);
            a[i + j + k] = ce_min(x, y);
          }
        }
      }
    }
  }
}

// OEMS-64 on (e, e+32) split-packing: reg r = [pos r, pos r+32].
// CE classes: both<32 -> plain pk pair (hi companion provably in network);
// y==x+32 -> within-register; x<32<=y -> cross (reg x lo <-> reg y-32 hi).
__device__ __forceinline__ void sort64_packed(unsigned (&a)[32]) {
#pragma unroll
  for (int p = 1; p < 64; p <<= 1) {
#pragma unroll
    for (int k = p; k >= 1; k >>= 1) {
#pragma unroll
      for (int j = k & (p - 1); j + k < 64; j += 2 * k) {
#pragma unroll
        for (int i = 0; i < k; ++i) {
          const int x = i + j, y = i + j + k;
          if (y < 64 && (x / (2 * p)) == (y / (2 * p))) {
            if (y < 32) {
              const unsigned A = a[x], B = a[y];
              a[x] = pk_max(A, B); a[y] = pk_min(A, B);
            } else if (x < 32) {
              if (y == x + 32) {              // within-register: [max,min]
                const unsigned A = a[x], S = hswap(A);
                a[x] = lh(pk_max(A, S), pk_min(A, S));
              } else {                        // cross: x lo <-> (y-32) hi
                const int ry = y - 32;
                const unsigned A = a[x], B = a[ry], Bs = hswap(B);
                const unsigned M = pk_max(A, Bs), m = pk_min(A, Bs);
                a[x]  = lh(M, A);             // lo=max(A.lo,B.hi), hi kept
                a[ry] = lh(B, hswap(m));      // lo kept, hi=min(A.lo,B.hi)
              }
            }
          }
        }
      }
    }
  }
}

// lgkm-only fence: orders this wave's own-LDS ops without draining vmcnt.
// Waves in the block use disjoint LDS slices => no s_barrier.
__device__ __forceinline__ void lds_fence() {
  asm volatile("s_waitcnt lgkmcnt(0)" ::: "memory");
  __builtin_amdgcn_sched_barrier(0);
}

__device__ __forceinline__ unsigned swz_xor8(unsigned x) {
  return (unsigned)__builtin_amdgcn_ds_swizzle((int)x, (8 << 10) | 0x1f);
}

__global__ __launch_bounds__(64 * WPB, 8) void seq_sparsemax_kernel(
    const float* __restrict__ in, float* __restrict__ out) {
  __shared__ __align__(16) unsigned lds[WPB * NSLOT * 128];  // 12 KiB

  const int lane = threadIdx.x & 63;
  const int wave = threadIdx.x >> 6;
  unsigned* __restrict__ sp = &lds[wave * NSLOT * 128];

  const int tid   = blockIdx.x * WPB + wave;   // tile index 0..8191
  const int b     = tid >> 10;
  const int chunk = tid & (NCHUNK - 1);
  const size_t base = (size_t)b * N_INST * T_DIM + (size_t)chunk * CHUNK + 4 * lane;

  const int f    = lane >> 4;          // this lane's frame (of 4)
  const int lt0  = 4 * (lane & 15);    // local time in frame, 0..60
  const bool lol = (lane & 8) == 0;    // lt0 < 32 (owns packed-dword writes)

  // ---- load float4, convert to packed f16: Ah[i] = [(t0,t1),(t2,t3)] ----
  unsigned Ah[N_INST][2];
#pragma unroll
  for (int i = 0; i < N_INST; ++i) {
    const float4 q = *reinterpret_cast<const float4*>(in + base + (size_t)i * T_DIM);
    Ah[i][0] = packh(f2h(q.x), f2h(q.y));
    Ah[i][1] = packh(f2h(q.z), f2h(q.w));
  }

  // ---- pass 1: packed OEMS-16 sorts both times of a pair at once ----
  unsigned nt2[2];   // packed negated taus, [-tau_even, -tau_odd]
#pragma unroll
  for (int p = 0; p < 2; ++p) {
    unsigned z[N_INST];
#pragma unroll
    for (int i = 0; i < N_INST; ++i) z[i] = Ah[i][p];
    sort_desc_oems<unsigned, N_INST>(z);
    float csl = 0.f, csh = 0.f, tl = -1e30f, th = -1e30f;
#pragma unroll
    for (int k = 0; k < N_INST; ++k) {
      csl += h2f(z[k]);       tl = fmaxf(tl, (csl - 1.f) * (1.f / (float)(k + 1)));
      csh += h2f(z[k] >> 16); th = fmaxf(th, (csh - 1.f) * (1.f / (float)(k + 1)));
    }
    nt2[p] = packh(f2h(tl), f2h(th)) ^ 0x80008000u;   // negate both halves
  }

  const unsigned zz = 0u;  // Y(i,p) = pk_max(Ah + (-tau), 0)

  // ---- staging + gather, 2 rounds (12-slot LDS, r3 overwrite scheme) ----
  // logical dword d of (slot s, frame fr) holds times (d, d+32) of the row;
  // physical dword = s*128 + fr*32 + (d ^ ((s&7)<<2)).
  const int i2 = lane & 15;            // this lane's pass-2 row: inst
  const int f2 = lane >> 4;            //                         frame
  unsigned w[32];

#pragma unroll
  for (int g = 0; g < 2; ++g) {
    if (g > 0) lds_fence();            // WAR: round-0 reads done
    const int i_lo = (g == 0) ? 0 : 12, i_hi = (g == 0) ? 12 : 16;
#pragma unroll
    for (int i = 0; i < N_INST; ++i) {
      if (i < i_lo || i >= i_hi) continue;
      const unsigned y0 = pk_max(pk_add(Ah[i][0], nt2[0]), zz);
      const unsigned y1 = pk_max(pk_add(Ah[i][1], nt2[1]), zz);
      const unsigned p0 = swz_xor8(y0);   // partner lane (^8): times +32
      const unsigned p1 = swz_xor8(y1);
      if (lol) {
        uint4 d;
        d.x = packh(y0, p0);              // [t=lt0+0, t+32]
        d.y = lh(y0 >> 16, p0);           // [t=lt0+1, t+32]
        d.z = packh(y1, p1);              // [t=lt0+2, t+32]
        d.w = lh(y1 >> 16, p1);           // [t=lt0+3, t+32]
        const int s = (i < 12) ? i : (i - 12);
        const int pd = s * 128 + f * 32 + (lt0 ^ ((s & 7) << 2));
        *reinterpret_cast<uint4*>(&sp[pd]) = d;
      }
    }
    lds_fence();                        // RAW: writes visible
    const bool mine = (g == 0) ? (i2 < 12) : (i2 >= 12);
    if (mine) {
      const int s = (i2 < 12) ? i2 : (i2 - 12);
#pragma unroll
      for (int v = 0; v < 8; ++v) {
        const int pd = s * 128 + f2 * 32 + ((4 * v) ^ ((s & 7) << 2));
        const uint4 d = *reinterpret_cast<const uint4*>(&sp[pd]);
        w[4 * v + 0] = d.x; w[4 * v + 1] = d.y;
        w[4 * v + 2] = d.z; w[4 * v + 3] = d.w;
      }
    }
  }

  // ---- pass 2: packed sort of this lane's 64-row, then tau (f32) ----
  sort64_packed(w);
  float csl = 0.f, csh = 0.f, bl = -1e30f, bh = -1e30f;
#pragma unroll
  for (int r = 0; r < 32; ++r) {        // ranks 1..32 (lo halves)
    csl += h2f(w[r]);
    bl = fmaxf(bl, (csl - 1.f) * (1.f / (float)(r + 1)));
  }
  const float dh = csl - 1.f;           // hi chain offset (ILP: chains split)
#pragma unroll
  for (int r = 0; r < 32; ++r) {        // ranks 33..64 (hi halves)
    csh += h2f(w[r] >> 16);
    bh = fmaxf(bh, (csh + dh) * (1.f / (float)(r + 33)));
  }
  const float best = fmaxf(bl, bh);
  __builtin_amdgcn_sched_barrier(0);    // don't hoist phase 3 into the sort

  // ---- phase 3: pull row-taus; Y from LDS (i>=4) or recompute (i<4);
  //      NON-TEMPORAL float4 stores (write-once data, keep L3 for input) ----
  const int slb = lane & 48;            // (lane>>4)*16: row-owner lane base
  const unsigned hsh = (lane & 8) ? 16u : 0u;   // my half in packed dwords
#pragma unroll
  for (int i = 0; i < N_INST; ++i) {
    const float taui = __int_as_float(__builtin_amdgcn_ds_bpermute(
        (slb | i) << 2, __float_as_int(best)));
    float y0, y1, y2, y3;
    if (i < 4) {                        // slots overwritten: recompute from Ah
      const unsigned a0 = pk_max(pk_add(Ah[i][0], nt2[0]), zz);
      const unsigned a1 = pk_max(pk_add(Ah[i][1], nt2[1]), zz);
      y0 = h2f(a0); y1 = h2f(a0 >> 16); y2 = h2f(a1); y3 = h2f(a1 >> 16);
    } else {
      const int s = (i < 12) ? i : (i - 12);
      const int pd = s * 128 + f * 32 + ((lt0 & 31) ^ ((s & 7) << 2));
      const uint4 d = *reinterpret_cast<const uint4*>(&sp[pd]);
      y0 = h2f(d.x >> hsh); y1 = h2f(d.y >> hsh);
      y2 = h2f(d.z >> hsh); y3 = h2f(d.w >> hsh);
    }
    f32x4 o;
    o.x = fmaxf(y0 - taui, 0.0f);
    o.y = fmaxf(y1 - taui, 0.0f);
    o.z = fmaxf(y2 - taui, 0.0f);
    o.w = fmaxf(y3 - taui, 0.0f);
    __builtin_nontemporal_store(
        o, reinterpret_cast<f32x4*>(out + base + (size_t)i * T_DIM));
  }
}

extern "C" void kernel_launch(void* const* d_in, const int* in_sizes, int n_in,
                              void* d_out, int out_size, void* d_ws, size_t ws_size,
                              hipStream_t stream) {
  const float* in = (const float*)d_in[0];
  float* out = (float*)d_out;
  const int grid = B_DIM * NCHUNK / WPB;  // 4096 blocks x 2 waves
  seq_sparsemax_kernel<<<grid, 64 * WPB, 0, stream>>>(in, out);
}